// Round 9
// baseline (539.359 us; speedup 1.0000x reference)
//
#include <hip/hip_runtime.h>
#include <math.h>

#define EMBED 128
#define NPB 128   // pairs per block

typedef short s16x8 __attribute__((ext_vector_type(8)));
typedef float f32x16 __attribute__((ext_vector_type(16)));
#define MF(a, b, c) __builtin_amdgcn_mfma_f32_32x32x16_bf16((a), (b), (c), 0, 0, 0)

// float -> bf16 bits, RNE
__device__ __forceinline__ unsigned short f2bf(float f) {
    unsigned u = __float_as_uint(f);
    return (unsigned short)((u + 0x7FFF + ((u >> 16) & 1)) >> 16);
}
__device__ __forceinline__ float bf2f(unsigned short h) {
    return __uint_as_float(((unsigned)h) << 16);
}

// ---------------------------------------------------------------------------
// pairs dtype detector (int64 vs int32 layout).
// ---------------------------------------------------------------------------
__global__ void detect_kernel(const unsigned int* __restrict__ pairs,
                              int* __restrict__ flag) {
    unsigned v = 0;
    int lane = threadIdx.x;
#pragma unroll
    for (int i = 0; i < 8; ++i) v |= pairs[2 * (lane * 8 + i) + 1];
    unsigned long long b = __ballot(v != 0);
    if (lane == 0) *flag = (b != 0ULL) ? 1 : 0;
}

// ---------------------------------------------------------------------------
// Setup: split W1 (512x128) and W2 (128x64) into bf16 hi/lo in FRAG-LINEAR
// layout: frag f = (jtile*K16 + kstep)*64 + lane; element e: the exact 8
// bf16 the MFMA B-operand lane needs -> wave reads are lane-consecutive 16B.
// ---------------------------------------------------------------------------
__global__ __launch_bounds__(256) void setup_w_kernel(
    const float* __restrict__ W1, const float* __restrict__ W2,
    unsigned short* __restrict__ W1Fh, unsigned short* __restrict__ W1Fl,
    unsigned short* __restrict__ W2Fh, unsigned short* __restrict__ W2Fl)
{
    int gid = blockIdx.x * 256 + threadIdx.x;
    if (gid < 8192) {                       // W1F
        int f = gid;
        int jt = f >> 11, r = f & 2047;
        int gk = r >> 6, lane = r & 63;
        int j = jt * 32 + (lane & 31);
        int kb = gk * 16 + (lane >> 5) * 8;
#pragma unroll
        for (int e = 0; e < 8; ++e) {
            float w = W1[(size_t)(kb + e) * 128 + j];
            unsigned short hb = f2bf(w);
            unsigned short lb = f2bf(w - bf2f(hb));
            W1Fh[(size_t)f * 8 + e] = hb;
            W1Fl[(size_t)f * 8 + e] = lb;
        }
    } else if (gid < 9216) {                // W2F
        int f = gid - 8192;
        int nt = f >> 9, r = f & 511;
        int gk = r >> 6, lane = r & 63;
        int i = nt * 32 + (lane & 31);
        int kb = gk * 16 + (lane >> 5) * 8;
#pragma unroll
        for (int e = 0; e < 8; ++e) {
            float w = W2[(size_t)(kb + e) * 64 + i];
            unsigned short hb = f2bf(w);
            unsigned short lb = f2bf(w - bf2f(hb));
            W2Fh[(size_t)f * 8 + e] = hb;
            W2Fl[(size_t)f * 8 + e] = lb;
        }
    }
}

// ---------------------------------------------------------------------------
// Per-chunk F-tile builder: loads the needed h slices fresh from global
// (L1/L2/L3-hot re-reads; round-9 spill fix — no 128-float register arrays).
// MODE: 0=hs, 1=ht, 2=hs*ht, 3=|hs-ht|.
// ---------------------------------------------------------------------------
template<int MODE>
__device__ __forceinline__ void build_chunk(
    unsigned short* __restrict__ fbH, unsigned short* __restrict__ fbL,
    const float4* __restrict__ hsP, const float4* __restrict__ htP,
    int pRow, int half8, int swzp)
{
#pragma unroll
    for (int gg = 0; gg < 8; ++gg) {
        float av[8], bv[8];
        if (MODE != 1) {
            float4 a0 = hsP[gg * 2], a1 = hsP[gg * 2 + 1];
            av[0] = a0.x; av[1] = a0.y; av[2] = a0.z; av[3] = a0.w;
            av[4] = a1.x; av[5] = a1.y; av[6] = a1.z; av[7] = a1.w;
        }
        if (MODE != 0) {
            float4 b0 = htP[gg * 2], b1 = htP[gg * 2 + 1];
            bv[0] = b0.x; bv[1] = b0.y; bv[2] = b0.z; bv[3] = b0.w;
            bv[4] = b1.x; bv[5] = b1.y; bv[6] = b1.z; bv[7] = b1.w;
        }
        s16x8 hv, lv;
#pragma unroll
        for (int e = 0; e < 8; ++e) {
            float v;
            if (MODE == 0)      v = av[e];
            else if (MODE == 1) v = bv[e];
            else if (MODE == 2) v = av[e] * bv[e];
            else                v = fabsf(av[e] - bv[e]);
            unsigned short hb = f2bf(v);
            unsigned short lb = f2bf(v - bf2f(hb));
            hv[e] = (short)hb; lv[e] = (short)lb;
        }
        int idx = pRow * 136 + ((half8 + gg) ^ swzp) * 8;
        *(s16x8*)&fbH[idx] = hv;
        *(s16x8*)&fbL[idx] = lv;
    }
}

// ---------------------------------------------------------------------------
// MFMA pair kernel: block = 128 pairs x 128 j, 4 waves (64p x 64j each).
// Full K=512 = [hs|ht|hs*ht|abs(hs-ht)], 4 chunks of 128k built in LDS as
// bf16 hi/lo; 3-pass split MFMA (hh+hl+lh). B-frags stream from frag-linear
// W1F/W2F. Layer 2 MFMA; layer 3 via LDS reduction (reuses fbH).
// ---------------------------------------------------------------------------
__global__ __launch_bounds__(256, 2) void pair_mfma_kernel(
    const float* __restrict__ h,
    const int* __restrict__ pairs,
    const int* __restrict__ flag,
    const unsigned short* __restrict__ W1Fh, const unsigned short* __restrict__ W1Fl,
    const unsigned short* __restrict__ W2Fh, const unsigned short* __restrict__ W2Fl,
    const float* __restrict__ b1, const float* __restrict__ b2,
    const float* __restrict__ W3, const float* __restrict__ b3,
    float* __restrict__ out, int npairs)
{
    __shared__ __align__(16) unsigned short fbH[128 * 136];
    __shared__ __align__(16) unsigned short fbL[128 * 136];
    __shared__ int sArr[NPB], tArr[NPB];

    int tid  = threadIdx.x;
    int lane = tid & 63;
    int w    = tid >> 6;
    int pb   = blockIdx.x * NPB;

    if (tid < NPB) {
        int p = pb + tid; if (p >= npairs) p = npairs - 1;
        int s, t;
        if (*flag == 0) { s = pairs[4 * p]; t = pairs[4 * p + 2]; }
        else            { s = pairs[2 * p]; t = pairs[2 * p + 1]; }
        sArr[tid] = s; tArr[tid] = t;
    }
    __syncthreads();

    // ---- F staging role: this thread builds row pRow, dim-half `half` ----
    int pRow  = tid & 127;
    int half  = tid >> 7;
    int half8 = half * 8;
    int swzp  = (pRow >> 3) & 7;
    const float4* hsP = (const float4*)(h + (size_t)sArr[pRow] * EMBED + half * 64);
    const float4* htP = (const float4*)(h + (size_t)tArr[pRow] * EMBED + half * 64);

    // ---- wave tile ----
    int prow = (w & 1) * 64;
    int jt0  = (w >> 1) * 2, jt1 = jt0 + 1;
    int jcol = (w >> 1) * 64;
    int ghalf = lane >> 5;
    int pA0 = prow + (lane & 31), pA1 = pA0 + 32;
    int oA0base = pA0 * 136, oA1base = pA1 * 136;
    int sw0 = (pA0 >> 3) & 7, sw1 = (pA1 >> 3) & 7;

    // acc init = b1 (bias folded)
    float bj0 = b1[jcol + (lane & 31)];
    float bj1 = b1[jcol + 32 + (lane & 31)];
    f32x16 acc00, acc01, acc10, acc11;
#pragma unroll
    for (int r = 0; r < 16; ++r) { acc00[r] = bj0; acc01[r] = bj1; acc10[r] = bj0; acc11[r] = bj1; }

#define L1_CHUNK(c) do {                                                     \
    _Pragma("unroll")                                                        \
    for (int ks = 0; ks < 8; ++ks) {                                         \
        int g = ks * 2 + ghalf;                                              \
        int o0 = oA0base + (g ^ sw0) * 8;                                    \
        int o1 = oA1base + (g ^ sw1) * 8;                                    \
        s16x8 aH0 = *(const s16x8*)&fbH[o0];                                 \
        s16x8 aL0 = *(const s16x8*)&fbL[o0];                                 \
        s16x8 aH1 = *(const s16x8*)&fbH[o1];                                 \
        s16x8 aL1 = *(const s16x8*)&fbL[o1];                                 \
        int gk = (c) * 8 + ks;                                               \
        size_t bi0 = ((size_t)(jt0 * 32 + gk) * 64 + lane) * 8;              \
        size_t bi1 = ((size_t)(jt1 * 32 + gk) * 64 + lane) * 8;              \
        s16x8 bH0 = *(const s16x8*)&W1Fh[bi0];                               \
        s16x8 bL0 = *(const s16x8*)&W1Fl[bi0];                               \
        s16x8 bH1 = *(const s16x8*)&W1Fh[bi1];                               \
        s16x8 bL1 = *(const s16x8*)&W1Fl[bi1];                               \
        acc00 = MF(aH0, bH0, acc00); acc00 = MF(aH0, bL0, acc00); acc00 = MF(aL0, bH0, acc00); \
        acc01 = MF(aH0, bH1, acc01); acc01 = MF(aH0, bL1, acc01); acc01 = MF(aL0, bH1, acc01); \
        acc10 = MF(aH1, bH0, acc10); acc10 = MF(aH1, bL0, acc10); acc10 = MF(aL1, bH0, acc10); \
        acc11 = MF(aH1, bH1, acc11); acc11 = MF(aH1, bL1, acc11); acc11 = MF(aL1, bH1, acc11); \
    } } while (0)

    // ---- 4 K-chunks: hs | ht | hs*ht | |hs-ht| ----
    build_chunk<0>(fbH, fbL, hsP, htP, pRow, half8, swzp);
    __syncthreads(); L1_CHUNK(0); __syncthreads();
    build_chunk<1>(fbH, fbL, hsP, htP, pRow, half8, swzp);
    __syncthreads(); L1_CHUNK(1); __syncthreads();
    build_chunk<2>(fbH, fbL, hsP, htP, pRow, half8, swzp);
    __syncthreads(); L1_CHUNK(2); __syncthreads();
    build_chunk<3>(fbH, fbL, hsP, htP, pRow, half8, swzp);
    __syncthreads(); L1_CHUNK(3); __syncthreads();

    // ---- x1 = relu(acc): write bf16 hi/lo back to LDS in A-layout ----
#define X1WR(ACC, m, n) do {                                                 \
    int jbase = jcol + (n) * 32 + (lane & 31);                               \
    int gj = jbase >> 3, jrem = jbase & 7;                                   \
    _Pragma("unroll")                                                        \
    for (int reg = 0; reg < 16; ++reg) {                                     \
        int pr = prow + (m) * 32 + (reg & 3) + 8 * (reg >> 2) + 4 * ghalf;   \
        float x = fmaxf(ACC[reg], 0.0f);                                     \
        unsigned short hb = f2bf(x);                                         \
        unsigned short lb = f2bf(x - bf2f(hb));                              \
        int idx = pr * 136 + ((gj ^ ((pr >> 3) & 7)) * 8) + jrem;            \
        fbH[idx] = hb; fbL[idx] = lb;                                        \
    } } while (0)

    X1WR(acc00, 0, 0); X1WR(acc01, 0, 1); X1WR(acc10, 1, 0); X1WR(acc11, 1, 1);
#undef X1WR
    __syncthreads();

    // ---- layer 2 MFMA: M=128, N=64, K=128 (3-pass) ----
    int pB0 = 64 * (w & 1) + (lane & 31), pB1 = pB0 + 32;
    int oB0base = pB0 * 136, oB1base = pB1 * 136;
    int sb0 = (pB0 >> 3) & 7, sb1 = (pB1 >> 3) & 7;
    int nt = w >> 1;
    int iCol = nt * 32 + (lane & 31);

    float b2v = b2[iCol];
    f32x16 c20, c21;
#pragma unroll
    for (int r = 0; r < 16; ++r) { c20[r] = b2v; c21[r] = b2v; }

#pragma unroll
    for (int ks = 0; ks < 8; ++ks) {
        int g = ks * 2 + ghalf;
        int o0 = oB0base + (g ^ sb0) * 8;
        int o1 = oB1base + (g ^ sb1) * 8;
        s16x8 aH0 = *(const s16x8*)&fbH[o0];
        s16x8 aL0 = *(const s16x8*)&fbL[o0];
        s16x8 aH1 = *(const s16x8*)&fbH[o1];
        s16x8 aL1 = *(const s16x8*)&fbL[o1];
        size_t bi = ((size_t)(nt * 8 + ks) * 64 + lane) * 8;
        s16x8 bH = *(const s16x8*)&W2Fh[bi];
        s16x8 bL = *(const s16x8*)&W2Fl[bi];
        c20 = MF(aH0, bH, c20); c20 = MF(aH0, bL, c20); c20 = MF(aL0, bH, c20);
        c21 = MF(aH1, bH, c21); c21 = MF(aH1, bL, c21); c21 = MF(aL1, bH, c21);
    }
    __syncthreads();   // all fbH/fbL reads done -> safe to reuse fbH as float

    // ---- layer 3: relu(x2).W3 partials into LDS [128][68], then row-sum ----
    float* red = (float*)fbH;
    {
        float w3v = W3[iCol];
#pragma unroll
        for (int reg = 0; reg < 16; ++reg) {
            int pr = 64 * (w & 1) + (reg & 3) + 8 * (reg >> 2) + 4 * ghalf;
            red[pr * 68 + iCol] = fmaxf(c20[reg], 0.0f) * w3v;
        }
#pragma unroll
        for (int reg = 0; reg < 16; ++reg) {
            int pr = 64 * (w & 1) + 32 + (reg & 3) + 8 * (reg >> 2) + 4 * ghalf;
            red[pr * 68 + iCol] = fmaxf(c21[reg], 0.0f) * w3v;
        }
    }
    __syncthreads();

    if (tid < NPB) {
        int p = pb + tid;
        if (p < npairs) {
            const float4* r4 = (const float4*)(red + tid * 68);
            float s = 0.0f;
#pragma unroll
            for (int q = 0; q < 16; ++q) {
                float4 v = r4[q];
                s += v.x + v.y + v.z + v.w;
            }
            out[p] = s + b3[0];
        }
    }
#undef L1_CHUNK
}

// ---------------------------------------------------------------------------
// Fallback: direct per-pair fp32 kernel (only if d_ws too small).
// ---------------------------------------------------------------------------
__global__ __launch_bounds__(256) void mlp_kernel(
    const float* __restrict__ h,
    const int* __restrict__ pairs,
    const int* __restrict__ flag,
    const float* __restrict__ W1, const float* __restrict__ b1,
    const float* __restrict__ W2, const float* __restrict__ b2,
    const float* __restrict__ W3, const float* __restrict__ b3,
    float* __restrict__ out, int npairs)
{
    int p = blockIdx.x * 256 + threadIdx.x;
    if (p >= npairs) return;
    int s, t;
    if (*flag == 0) { s = pairs[4 * p]; t = pairs[4 * p + 2]; }
    else            { s = pairs[2 * p]; t = pairs[2 * p + 1]; }
    const float4* hs4 = (const float4*)(h + (size_t)s * EMBED);
    const float4* ht4 = (const float4*)(h + (size_t)t * EMBED);
    float acc[128];
#pragma unroll
    for (int j = 0; j < 128; ++j) acc[j] = b1[j];
#pragma unroll 1
    for (int d4 = 0; d4 < EMBED / 4; ++d4) {
        float4 a = hs4[d4]; float4 b = ht4[d4];
        float av[4] = {a.x, a.y, a.z, a.w};
        float bv[4] = {b.x, b.y, b.z, b.w};
#pragma unroll
        for (int dd = 0; dd < 4; ++dd) {
            int k = d4 * 4 + dd;
            float f0 = av[dd], f1 = bv[dd];
            float f2 = f0 * f1, f3 = fabsf(f0 - f1);
            const float* w0 = W1 + (size_t)k * 128;
            const float* w1r = w0 + 128 * 128;
            const float* w2r = w0 + 256 * 128;
            const float* w3r = w0 + 384 * 128;
#pragma unroll
            for (int j = 0; j < 128; ++j) {
                float v0 = acc[j];
                v0 = fmaf(f0, w0[j], v0); v0 = fmaf(f1, w1r[j], v0);
                v0 = fmaf(f2, w2r[j], v0); v0 = fmaf(f3, w3r[j], v0);
                acc[j] = v0;
            }
        }
    }
#pragma unroll
    for (int j = 0; j < 128; ++j) acc[j] = fmaxf(acc[j], 0.0f);
    float x2[64];
#pragma unroll
    for (int j = 0; j < 64; ++j) x2[j] = b2[j];
#pragma unroll
    for (int k = 0; k < 128; ++k) {
        float xv = acc[k];
#pragma unroll
        for (int j = 0; j < 64; ++j)
            x2[j] = fmaf(xv, W2[(size_t)k * 64 + j], x2[j]);
    }
    float lg = b3[0];
#pragma unroll
    for (int k = 0; k < 64; ++k)
        lg = fmaf(fmaxf(x2[k], 0.0f), W3[k], lg);
    out[p] = lg;
}

extern "C" void kernel_launch(void* const* d_in, const int* in_sizes, int n_in,
                              void* d_out, int out_size, void* d_ws, size_t ws_size,
                              hipStream_t stream) {
    const float* h   = (const float*)d_in[0];
    const int* pairs = (const int*)d_in[1];
    const float* W1  = (const float*)d_in[2];
    const float* b1  = (const float*)d_in[3];
    const float* W2  = (const float*)d_in[4];
    const float* b2  = (const float*)d_in[5];
    const float* W3  = (const float*)d_in[6];
    const float* b3  = (const float*)d_in[7];
    float* out = (float*)d_out;

    int npairs = out_size;

    int* flag = (int*)d_ws;
    unsigned short* base = (unsigned short*)((char*)d_ws + 16);
    unsigned short* W1Fh = base;                 // 65536 ushort
    unsigned short* W1Fl = base + 65536;         // 65536
    unsigned short* W2Fh = base + 131072;        // 8192
    unsigned short* W2Fl = base + 139264;        // 8192
    size_t need = 16 + (size_t)(65536 * 2 + 8192 * 2) * sizeof(unsigned short);

    detect_kernel<<<1, 64, 0, stream>>>((const unsigned int*)pairs, flag);

    if (ws_size >= need) {
        setup_w_kernel<<<36, 256, 0, stream>>>(W1, W2, W1Fh, W1Fl, W2Fh, W2Fl);
        pair_mfma_kernel<<<(npairs + NPB - 1) / NPB, 256, 0, stream>>>(
            h, pairs, flag, W1Fh, W1Fl, W2Fh, W2Fl, b1, b2, W3, b3, out, npairs);
    } else {
        mlp_kernel<<<(npairs + 255) / 256, 256, 0, stream>>>(
            h, pairs, flag, W1, b1, W2, b2, W3, b3, out, npairs);
    }
}

// Round 10
// 278.411 us; speedup vs baseline: 1.9373x; 1.9373x over previous
//
#include <hip/hip_runtime.h>
#include <math.h>

#define EMBED 128
#define NPB 128   // pairs per block

typedef short s16x8 __attribute__((ext_vector_type(8)));
typedef float f32x16 __attribute__((ext_vector_type(16)));
#define MF(a, b, c) __builtin_amdgcn_mfma_f32_32x32x16_bf16((a), (b), (c), 0, 0, 0)

// float -> bf16 bits, RNE
__device__ __forceinline__ unsigned short f2bf(float f) {
    unsigned u = __float_as_uint(f);
    return (unsigned short)((u + 0x7FFF + ((u >> 16) & 1)) >> 16);
}
__device__ __forceinline__ float bf2f(unsigned short h) {
    return __uint_as_float(((unsigned)h) << 16);
}

// ---------------------------------------------------------------------------
// pairs dtype detector (int64 vs int32 layout).
// ---------------------------------------------------------------------------
__global__ void detect_kernel(const unsigned int* __restrict__ pairs,
                              int* __restrict__ flag) {
    unsigned v = 0;
    int lane = threadIdx.x;
#pragma unroll
    for (int i = 0; i < 8; ++i) v |= pairs[2 * (lane * 8 + i) + 1];
    unsigned long long b = __ballot(v != 0);
    if (lane == 0) *flag = (b != 0ULL) ? 1 : 0;
}

// ---------------------------------------------------------------------------
// Setup: split W1 (512x128) and W2 (128x64) into bf16 hi/lo in FRAG-LINEAR
// layout (exact per-lane MFMA B-operand order; validated rounds 8-9).
// ---------------------------------------------------------------------------
__global__ __launch_bounds__(256) void setup_w_kernel(
    const float* __restrict__ W1, const float* __restrict__ W2,
    unsigned short* __restrict__ W1Fh, unsigned short* __restrict__ W1Fl,
    unsigned short* __restrict__ W2Fh, unsigned short* __restrict__ W2Fl)
{
    int gid = blockIdx.x * 256 + threadIdx.x;
    if (gid < 8192) {                       // W1F
        int f = gid;
        int jt = f >> 11, r = f & 2047;
        int gk = r >> 6, lane = r & 63;
        int j = jt * 32 + (lane & 31);
        int kb = gk * 16 + (lane >> 5) * 8;
#pragma unroll
        for (int e = 0; e < 8; ++e) {
            float w = W1[(size_t)(kb + e) * 128 + j];
            unsigned short hb = f2bf(w);
            unsigned short lb = f2bf(w - bf2f(hb));
            W1Fh[(size_t)f * 8 + e] = hb;
            W1Fl[(size_t)f * 8 + e] = lb;
        }
    } else if (gid < 9216) {                // W2F
        int f = gid - 8192;
        int nt = f >> 9, r = f & 511;
        int gk = r >> 6, lane = r & 63;
        int i = nt * 32 + (lane & 31);
        int kb = gk * 16 + (lane >> 5) * 8;
#pragma unroll
        for (int e = 0; e < 8; ++e) {
            float w = W2[(size_t)(kb + e) * 64 + i];
            unsigned short hb = f2bf(w);
            unsigned short lb = f2bf(w - bf2f(hb));
            W2Fh[(size_t)f * 8 + e] = hb;
            W2Fl[(size_t)f * 8 + e] = lb;
        }
    }
}

// ---------------------------------------------------------------------------
// On-the-fly A-fragment: read 8 f32 of hs/ht from LDS, compute feature,
// split to bf16 hi/lo. MODE: 0=hs, 1=ht, 2=hs*ht, 3=|hs-ht|.
// ---------------------------------------------------------------------------
template<int MODE>
__device__ __forceinline__ void make_frag(
    const float* __restrict__ hsL, const float* __restrict__ htL,
    int row, int dcol, s16x8& aH, s16x8& aL)
{
    float av[8], bv[8];
    if (MODE != 1) {
        float4 a0 = *(const float4*)(hsL + row * 68 + dcol);
        float4 a1 = *(const float4*)(hsL + row * 68 + dcol + 4);
        av[0] = a0.x; av[1] = a0.y; av[2] = a0.z; av[3] = a0.w;
        av[4] = a1.x; av[5] = a1.y; av[6] = a1.z; av[7] = a1.w;
    }
    if (MODE != 0) {
        float4 b0 = *(const float4*)(htL + row * 68 + dcol);
        float4 b1 = *(const float4*)(htL + row * 68 + dcol + 4);
        bv[0] = b0.x; bv[1] = b0.y; bv[2] = b0.z; bv[3] = b0.w;
        bv[4] = b1.x; bv[5] = b1.y; bv[6] = b1.z; bv[7] = b1.w;
    }
#pragma unroll
    for (int e = 0; e < 8; ++e) {
        float v;
        if (MODE == 0)      v = av[e];
        else if (MODE == 1) v = bv[e];
        else if (MODE == 2) v = av[e] * bv[e];
        else                v = fabsf(av[e] - bv[e]);
        unsigned short hb = f2bf(v);
        unsigned short lb = f2bf(v - bf2f(hb));
        aH[e] = (short)hb; aL[e] = (short)lb;
    }
}

// One chunk's 4 k-steps within the currently-staged 64-dim phase.
template<int MODE>
__device__ __forceinline__ void l1_phase(
    const float* __restrict__ hsL, const float* __restrict__ htL,
    const unsigned short* __restrict__ W1Fh, const unsigned short* __restrict__ W1Fl,
    int pA0, int pA1, int ghalf, int lane, int jt0, int jt1, int gkbase,
    f32x16& acc00, f32x16& acc01, f32x16& acc10, f32x16& acc11)
{
#pragma unroll
    for (int ks = 0; ks < 4; ++ks) {
        int dcol = ks * 16 + ghalf * 8;
        s16x8 aH0, aL0, aH1, aL1;
        make_frag<MODE>(hsL, htL, pA0, dcol, aH0, aL0);
        make_frag<MODE>(hsL, htL, pA1, dcol, aH1, aL1);
        int gk = gkbase + ks;
        size_t bi0 = ((size_t)(jt0 * 32 + gk) * 64 + lane) * 8;
        size_t bi1 = ((size_t)(jt1 * 32 + gk) * 64 + lane) * 8;
        s16x8 bH0 = *(const s16x8*)&W1Fh[bi0];
        s16x8 bL0 = *(const s16x8*)&W1Fl[bi0];
        s16x8 bH1 = *(const s16x8*)&W1Fh[bi1];
        s16x8 bL1 = *(const s16x8*)&W1Fl[bi1];
        acc00 = MF(aH0, bH0, acc00); acc00 = MF(aH0, bL0, acc00); acc00 = MF(aL0, bH0, acc00);
        acc01 = MF(aH0, bH1, acc01); acc01 = MF(aH0, bL1, acc01); acc01 = MF(aL0, bH1, acc01);
        acc10 = MF(aH1, bH0, acc10); acc10 = MF(aH1, bL0, acc10); acc10 = MF(aL1, bH0, acc10);
        acc11 = MF(aH1, bH1, acc11); acc11 = MF(aH1, bL1, acc11); acc11 = MF(aL1, bH1, acc11);
    }
}

// ---------------------------------------------------------------------------
// MFMA pair kernel v3: h staged in LDS fp32 (two 64-dim phases), A-frags
// built on the fly (no fb staging, no per-chunk barriers, no reg arrays).
// x1 fragment buffer aliases the h region after the last L1 read.
// ---------------------------------------------------------------------------
__global__ __launch_bounds__(256, 2) void pair_mfma_kernel(
    const float* __restrict__ h,
    const int* __restrict__ pairs,
    const int* __restrict__ flag,
    const unsigned short* __restrict__ W1Fh, const unsigned short* __restrict__ W1Fl,
    const unsigned short* __restrict__ W2Fh, const unsigned short* __restrict__ W2Fl,
    const float* __restrict__ b1, const float* __restrict__ b2,
    const float* __restrict__ W3, const float* __restrict__ b3,
    float* __restrict__ out, int npairs)
{
    __shared__ __align__(16) char buf[69632];
    __shared__ int sArr[NPB], tArr[NPB];
    float* hsL = (float*)buf;                          // [128][68] f32
    float* htL = (float*)(buf + 34816);                // [128][68] f32
    unsigned short* fbH = (unsigned short*)buf;        // [128][136] us (alias)
    unsigned short* fbL = (unsigned short*)(buf + 34816);

    int tid  = threadIdx.x;
    int lane = tid & 63;
    int w    = tid >> 6;
    int pb   = blockIdx.x * NPB;

    if (tid < NPB) {
        int p = pb + tid; if (p >= npairs) p = npairs - 1;
        int s, t;
        if (*flag == 0) { s = pairs[4 * p]; t = pairs[4 * p + 2]; }
        else            { s = pairs[2 * p]; t = pairs[2 * p + 1]; }
        sArr[tid] = s; tArr[tid] = t;
    }
    __syncthreads();

    // staging role: thread = (row, node)
    int r  = tid & 127;
    int nd = tid >> 7;
    const float* gsrc = h + (size_t)(nd ? tArr[r] : sArr[r]) * EMBED;
    float* ldst = (nd ? htL : hsL) + r * 68;

    // wave tile
    int prow = (w & 1) * 64;
    int jt0  = (w >> 1) * 2, jt1 = jt0 + 1;
    int jcol = (w >> 1) * 64;
    int ghalf = lane >> 5;
    int pA0 = prow + (lane & 31), pA1 = pA0 + 32;

    float bj0 = b1[jcol + (lane & 31)];
    float bj1 = b1[jcol + 32 + (lane & 31)];
    f32x16 acc00, acc01, acc10, acc11;
#pragma unroll
    for (int rg = 0; rg < 16; ++rg) { acc00[rg] = bj0; acc01[rg] = bj1; acc10[rg] = bj0; acc11[rg] = bj1; }

    // ---- phase 0: dims 0..63 ----
    {
        const float4* s4 = (const float4*)gsrc;
        float4* d4 = (float4*)ldst;
#pragma unroll
        for (int q = 0; q < 16; ++q) d4[q] = s4[q];
    }
    __syncthreads();
    l1_phase<0>(hsL, htL, W1Fh, W1Fl, pA0, pA1, ghalf, lane, jt0, jt1,  0, acc00, acc01, acc10, acc11);
    l1_phase<1>(hsL, htL, W1Fh, W1Fl, pA0, pA1, ghalf, lane, jt0, jt1,  8, acc00, acc01, acc10, acc11);
    l1_phase<2>(hsL, htL, W1Fh, W1Fl, pA0, pA1, ghalf, lane, jt0, jt1, 16, acc00, acc01, acc10, acc11);
    l1_phase<3>(hsL, htL, W1Fh, W1Fl, pA0, pA1, ghalf, lane, jt0, jt1, 24, acc00, acc01, acc10, acc11);
    __syncthreads();

    // ---- phase 1: dims 64..127 (same LDS slots) ----
    {
        const float4* s4 = (const float4*)(gsrc + 64);
        float4* d4 = (float4*)ldst;
#pragma unroll
        for (int q = 0; q < 16; ++q) d4[q] = s4[q];
    }
    __syncthreads();
    l1_phase<0>(hsL, htL, W1Fh, W1Fl, pA0, pA1, ghalf, lane, jt0, jt1,  4, acc00, acc01, acc10, acc11);
    l1_phase<1>(hsL, htL, W1Fh, W1Fl, pA0, pA1, ghalf, lane, jt0, jt1, 12, acc00, acc01, acc10, acc11);
    l1_phase<2>(hsL, htL, W1Fh, W1Fl, pA0, pA1, ghalf, lane, jt0, jt1, 20, acc00, acc01, acc10, acc11);
    l1_phase<3>(hsL, htL, W1Fh, W1Fl, pA0, pA1, ghalf, lane, jt0, jt1, 28, acc00, acc01, acc10, acc11);
    __syncthreads();   // h region dead -> fb may alias it

    // ---- x1 = relu(acc): bf16 hi/lo into fb (A-layout, granule XOR) ----
#define X1WR(ACC, m, n) do {                                                 \
    int jbase = jcol + (n) * 32 + (lane & 31);                               \
    int gj = jbase >> 3, jrem = jbase & 7;                                   \
    _Pragma("unroll")                                                        \
    for (int reg = 0; reg < 16; ++reg) {                                     \
        int pr = prow + (m) * 32 + (reg & 3) + 8 * (reg >> 2) + 4 * ghalf;   \
        float x = fmaxf(ACC[reg], 0.0f);                                     \
        unsigned short hb = f2bf(x);                                         \
        unsigned short lb = f2bf(x - bf2f(hb));                              \
        int idx = pr * 136 + ((gj ^ ((pr >> 3) & 7)) * 8) + jrem;            \
        fbH[idx] = hb; fbL[idx] = lb;                                        \
    } } while (0)

    X1WR(acc00, 0, 0); X1WR(acc01, 0, 1); X1WR(acc10, 1, 0); X1WR(acc11, 1, 1);
#undef X1WR
    __syncthreads();

    // ---- layer 2 MFMA: M=128, N=64, K=128 (3-pass) ----
    int pB0 = 64 * (w & 1) + (lane & 31), pB1 = pB0 + 32;
    int oB0base = pB0 * 136, oB1base = pB1 * 136;
    int sb0 = (pB0 >> 3) & 7, sb1 = (pB1 >> 3) & 7;
    int nt = w >> 1;
    int iCol = nt * 32 + (lane & 31);

    float b2v = b2[iCol];
    f32x16 c20, c21;
#pragma unroll
    for (int rg = 0; rg < 16; ++rg) { c20[rg] = b2v; c21[rg] = b2v; }

#pragma unroll
    for (int ks = 0; ks < 8; ++ks) {
        int g = ks * 2 + ghalf;
        int o0 = oB0base + (g ^ sb0) * 8;
        int o1 = oB1base + (g ^ sb1) * 8;
        s16x8 aH0 = *(const s16x8*)&fbH[o0];
        s16x8 aL0 = *(const s16x8*)&fbL[o0];
        s16x8 aH1 = *(const s16x8*)&fbH[o1];
        s16x8 aL1 = *(const s16x8*)&fbL[o1];
        size_t bi = ((size_t)(nt * 8 + ks) * 64 + lane) * 8;
        s16x8 bH = *(const s16x8*)&W2Fh[bi];
        s16x8 bL = *(const s16x8*)&W2Fl[bi];
        c20 = MF(aH0, bH, c20); c20 = MF(aH0, bL, c20); c20 = MF(aL0, bH, c20);
        c21 = MF(aH1, bH, c21); c21 = MF(aH1, bL, c21); c21 = MF(aL1, bH, c21);
    }
    __syncthreads();   // fb reads done -> reuse region as float reduction buf

    // ---- layer 3: relu(x2).W3 partials into LDS [128][68], then row-sum ----
    float* red = (float*)buf;
    {
        float w3v = W3[iCol];
#pragma unroll
        for (int reg = 0; reg < 16; ++reg) {
            int pr = 64 * (w & 1) + (reg & 3) + 8 * (reg >> 2) + 4 * ghalf;
            red[pr * 68 + iCol] = fmaxf(c20[reg], 0.0f) * w3v;
        }
#pragma unroll
        for (int reg = 0; reg < 16; ++reg) {
            int pr = 64 * (w & 1) + 32 + (reg & 3) + 8 * (reg >> 2) + 4 * ghalf;
            red[pr * 68 + iCol] = fmaxf(c21[reg], 0.0f) * w3v;
        }
    }
    __syncthreads();

    if (tid < NPB) {
        int p = pb + tid;
        if (p < npairs) {
            const float4* r4 = (const float4*)(red + tid * 68);
            float s = 0.0f;
#pragma unroll
            for (int q = 0; q < 16; ++q) {
                float4 v = r4[q];
                s += v.x + v.y + v.z + v.w;
            }
            out[p] = s + b3[0];
        }
    }
}

// ---------------------------------------------------------------------------
// Fallback: direct per-pair fp32 kernel (only if d_ws too small).
// ---------------------------------------------------------------------------
__global__ __launch_bounds__(256) void mlp_kernel(
    const float* __restrict__ h,
    const int* __restrict__ pairs,
    const int* __restrict__ flag,
    const float* __restrict__ W1, const float* __restrict__ b1,
    const float* __restrict__ W2, const float* __restrict__ b2,
    const float* __restrict__ W3, const float* __restrict__ b3,
    float* __restrict__ out, int npairs)
{
    int p = blockIdx.x * 256 + threadIdx.x;
    if (p >= npairs) return;
    int s, t;
    if (*flag == 0) { s = pairs[4 * p]; t = pairs[4 * p + 2]; }
    else            { s = pairs[2 * p]; t = pairs[2 * p + 1]; }
    const float4* hs4 = (const float4*)(h + (size_t)s * EMBED);
    const float4* ht4 = (const float4*)(h + (size_t)t * EMBED);
    float acc[128];
#pragma unroll
    for (int j = 0; j < 128; ++j) acc[j] = b1[j];
#pragma unroll 1
    for (int d4 = 0; d4 < EMBED / 4; ++d4) {
        float4 a = hs4[d4]; float4 b = ht4[d4];
        float av[4] = {a.x, a.y, a.z, a.w};
        float bv[4] = {b.x, b.y, b.z, b.w};
#pragma unroll
        for (int dd = 0; dd < 4; ++dd) {
            int k = d4 * 4 + dd;
            float f0 = av[dd], f1 = bv[dd];
            float f2 = f0 * f1, f3 = fabsf(f0 - f1);
            const float* w0 = W1 + (size_t)k * 128;
            const float* w1r = w0 + 128 * 128;
            const float* w2r = w0 + 256 * 128;
            const float* w3r = w0 + 384 * 128;
#pragma unroll
            for (int j = 0; j < 128; ++j) {
                float v0 = acc[j];
                v0 = fmaf(f0, w0[j], v0); v0 = fmaf(f1, w1r[j], v0);
                v0 = fmaf(f2, w2r[j], v0); v0 = fmaf(f3, w3r[j], v0);
                acc[j] = v0;
            }
        }
    }
#pragma unroll
    for (int j = 0; j < 128; ++j) acc[j] = fmaxf(acc[j], 0.0f);
    float x2[64];
#pragma unroll
    for (int j = 0; j < 64; ++j) x2[j] = b2[j];
#pragma unroll
    for (int k = 0; k < 128; ++k) {
        float xv = acc[k];
#pragma unroll
        for (int j = 0; j < 64; ++j)
            x2[j] = fmaf(xv, W2[(size_t)k * 64 + j], x2[j]);
    }
    float lg = b3[0];
#pragma unroll
    for (int k = 0; k < 64; ++k)
        lg = fmaf(fmaxf(x2[k], 0.0f), W3[k], lg);
    out[p] = lg;
}

extern "C" void kernel_launch(void* const* d_in, const int* in_sizes, int n_in,
                              void* d_out, int out_size, void* d_ws, size_t ws_size,
                              hipStream_t stream) {
    const float* h   = (const float*)d_in[0];
    const int* pairs = (const int*)d_in[1];
    const float* W1  = (const float*)d_in[2];
    const float* b1  = (const float*)d_in[3];
    const float* W2  = (const float*)d_in[4];
    const float* b2  = (const float*)d_in[5];
    const float* W3  = (const float*)d_in[6];
    const float* b3  = (const float*)d_in[7];
    float* out = (float*)d_out;

    int npairs = out_size;

    int* flag = (int*)d_ws;
    unsigned short* base = (unsigned short*)((char*)d_ws + 16);
    unsigned short* W1Fh = base;                 // 65536 ushort
    unsigned short* W1Fl = base + 65536;         // 65536
    unsigned short* W2Fh = base + 131072;        // 8192
    unsigned short* W2Fl = base + 139264;        // 8192
    size_t need = 16 + (size_t)(65536 * 2 + 8192 * 2) * sizeof(unsigned short);

    detect_kernel<<<1, 64, 0, stream>>>((const unsigned int*)pairs, flag);

    if (ws_size >= need) {
        setup_w_kernel<<<36, 256, 0, stream>>>(W1, W2, W1Fh, W1Fl, W2Fh, W2Fl);
        pair_mfma_kernel<<<(npairs + NPB - 1) / NPB, 256, 0, stream>>>(
            h, pairs, flag, W1Fh, W1Fl, W2Fh, W2Fl, b1, b2, W3, b3, out, npairs);
    } else {
        mlp_kernel<<<(npairs + 255) / 256, 256, 0, stream>>>(
            h, pairs, flag, W1, b1, W2, b2, W3, b3, out, npairs);
    }
}